// Round 4
// baseline (46.826 us; speedup 1.0000x reference)
//
#include <hip/hip_runtime.h>
#include <hip/hip_bf16.h>
#include <math.h>

typedef float  f32x4  __attribute__((ext_vector_type(4)));
typedef short  s16x4  __attribute__((ext_vector_type(4)));
typedef short  s16x8  __attribute__((ext_vector_type(8)));
typedef unsigned short u16;

__device__ inline u16 f2b(float f) {
    __hip_bfloat16 h = __float2bfloat16(f);
    return *reinterpret_cast<u16*>(&h);
}

// ---------------------------------------------------------------------------
// K1: fused QKV projection + RoPE + RMSNorm.
// GEMM M=2048 N=1024 K=512; A = x f32 (cast->bf16 on stage), B = Wq|Wk|Wv f32
// (transpose-cast on stage). 64x64 tile / 4 waves, each wave a 32x32 quadrant.
// Epilogue: acc -> LDS f32 [64][68]; per row (=t) apply RoPE(d,d+32)+RMS for
// q/k tiles (each n-tile == one head), plain cast for v; store bf16.
// ---------------------------------------------------------------------------
__global__ __launch_bounds__(256) void qkv_fused(const float* __restrict__ x,
    const float* __restrict__ Wq, const float* __restrict__ Wk,
    const float* __restrict__ Wv, const float* __restrict__ cosT,
    const float* __restrict__ sinT, const float* __restrict__ qw,
    const float* __restrict__ kw, u16* __restrict__ qnb,
    u16* __restrict__ knb, u16* __restrict__ vb)
{
    __shared__ u16 Ash[64][72];
    __shared__ u16 Bsh[64][72];
    __shared__ float Osh[64][68];
    const int tid = threadIdx.x;
    const int bx = blockIdx.x;                 // n-tile: 0-7 q, 8-11 k, 12-15 v
    const int m0 = blockIdx.y * 64;
    const float* W; int ldb, ncol0;
    if (bx < 8)       { W = Wq; ldb = 512; ncol0 = bx * 64; }
    else if (bx < 12) { W = Wk; ldb = 256; ncol0 = (bx - 8) * 64; }
    else              { W = Wv; ldb = 256; ncol0 = (bx - 12) * 64; }

    const int lane = tid & 63, wv = tid >> 6;
    const int q = lane & 15, g = lane >> 4;
    const int wm = (wv & 1) * 32, wn = (wv >> 1) * 32;
    const int sr = tid >> 2, sc = (tid & 3) * 16;   // A-stage: row, 16-float chunk
    f32x4 acc[2][2] = {{{0,0,0,0},{0,0,0,0}},{{0,0,0,0},{0,0,0,0}}};

    for (int k0 = 0; k0 < 512; k0 += 64) {
        // A: x[m0+sr][k0+sc .. +15] f32 -> bf16
        float4 a0 = *(const float4*)(x + (size_t)(m0 + sr) * 512 + k0 + sc);
        float4 a1 = *(const float4*)(x + (size_t)(m0 + sr) * 512 + k0 + sc + 4);
        float4 a2 = *(const float4*)(x + (size_t)(m0 + sr) * 512 + k0 + sc + 8);
        float4 a3 = *(const float4*)(x + (size_t)(m0 + sr) * 512 + k0 + sc + 12);
        // B: W[k0+sr][ncol0+sc .. +15] f32, scatter transposed
        float4 b0 = *(const float4*)(W + (size_t)(k0 + sr) * ldb + ncol0 + sc);
        float4 b1 = *(const float4*)(W + (size_t)(k0 + sr) * ldb + ncol0 + sc + 4);
        float4 b2 = *(const float4*)(W + (size_t)(k0 + sr) * ldb + ncol0 + sc + 8);
        float4 b3 = *(const float4*)(W + (size_t)(k0 + sr) * ldb + ncol0 + sc + 12);
        __syncthreads();
        ushort4 av;
        av = (ushort4){f2b(a0.x), f2b(a0.y), f2b(a0.z), f2b(a0.w)}; *(ushort4*)&Ash[sr][sc]      = av;
        av = (ushort4){f2b(a1.x), f2b(a1.y), f2b(a1.z), f2b(a1.w)}; *(ushort4*)&Ash[sr][sc + 4]  = av;
        av = (ushort4){f2b(a2.x), f2b(a2.y), f2b(a2.z), f2b(a2.w)}; *(ushort4*)&Ash[sr][sc + 8]  = av;
        av = (ushort4){f2b(a3.x), f2b(a3.y), f2b(a3.z), f2b(a3.w)}; *(ushort4*)&Ash[sr][sc + 12] = av;
        Bsh[sc + 0][sr]  = f2b(b0.x); Bsh[sc + 1][sr]  = f2b(b0.y);
        Bsh[sc + 2][sr]  = f2b(b0.z); Bsh[sc + 3][sr]  = f2b(b0.w);
        Bsh[sc + 4][sr]  = f2b(b1.x); Bsh[sc + 5][sr]  = f2b(b1.y);
        Bsh[sc + 6][sr]  = f2b(b1.z); Bsh[sc + 7][sr]  = f2b(b1.w);
        Bsh[sc + 8][sr]  = f2b(b2.x); Bsh[sc + 9][sr]  = f2b(b2.y);
        Bsh[sc + 10][sr] = f2b(b2.z); Bsh[sc + 11][sr] = f2b(b2.w);
        Bsh[sc + 12][sr] = f2b(b3.x); Bsh[sc + 13][sr] = f2b(b3.y);
        Bsh[sc + 14][sr] = f2b(b3.z); Bsh[sc + 15][sr] = f2b(b3.w);
        __syncthreads();
#pragma unroll
        for (int kk = 0; kk < 64; kk += 32) {
            s16x8 af0 = *(const s16x8*)&Ash[wm + q][kk + g*8];
            s16x8 af1 = *(const s16x8*)&Ash[wm + 16 + q][kk + g*8];
            s16x8 bf0 = *(const s16x8*)&Bsh[wn + q][kk + g*8];
            s16x8 bf1 = *(const s16x8*)&Bsh[wn + 16 + q][kk + g*8];
            acc[0][0] = __builtin_amdgcn_mfma_f32_16x16x32_bf16(af0, bf0, acc[0][0], 0, 0, 0);
            acc[0][1] = __builtin_amdgcn_mfma_f32_16x16x32_bf16(af0, bf1, acc[0][1], 0, 0, 0);
            acc[1][0] = __builtin_amdgcn_mfma_f32_16x16x32_bf16(af1, bf0, acc[1][0], 0, 0, 0);
            acc[1][1] = __builtin_amdgcn_mfma_f32_16x16x32_bf16(af1, bf1, acc[1][1], 0, 0, 0);
        }
    }
    // acc -> Osh (row = m in tile, col = d within head)
#pragma unroll
    for (int mt = 0; mt < 2; ++mt)
#pragma unroll
        for (int nt = 0; nt < 2; ++nt)
#pragma unroll
            for (int r = 0; r < 4; ++r)
                Osh[wm + mt*16 + g*4 + r][wn + nt*16 + q] = acc[mt][nt][r];
    __syncthreads();
    // Per-row epilogue: wave wv owns rows wv*16 .. wv*16+15; lane = d
#pragma unroll 1
    for (int ii = 0; ii < 16; ++ii) {
        const int row = wv * 16 + ii;
        const int t = m0 + row;
        if (bx >= 12) {   // V: plain cast
            vb[(size_t)t * 256 + (bx - 12) * 64 + lane] = f2b(Osh[row][lane]);
            continue;
        }
        float y = Osh[row][lane];
        float o = Osh[row][lane ^ 32];
        float c = cosT[t * 32 + (lane & 31)];
        float s = sinT[t * 32 + (lane & 31)];
        float r = (lane < 32) ? (y * c - o * s) : (y * c + o * s);
        float ss = r * r;
#pragma unroll
        for (int off = 32; off; off >>= 1) ss += __shfl_xor(ss, off);
        float scale = rsqrtf(ss * (1.0f / 64.0f) + 1e-6f);
        if (bx < 8) qnb[(size_t)t * 512 + bx * 64 + lane]       = f2b(r * scale * qw[lane]);
        else        knb[(size_t)t * 256 + (bx - 8) * 64 + lane] = f2b(r * scale * kw[lane]);
    }
}

// ---------------------------------------------------------------------------
// K2: MFMA sliding-window attention (unchanged from verified round-3 kernel).
// Block = (h, 64-q tile), 4 waves x 16 q. S^T = K·Q^T (16x16x32), P^T rows
// land in the 16x16x16 k-operand layout, O^T = V^T·P^T, LDS transpose out.
// ---------------------------------------------------------------------------
__global__ __launch_bounds__(256) void swa_mfma(const u16* __restrict__ qnb,
    const u16* __restrict__ knb, const u16* __restrict__ vb,
    u16* __restrict__ attb)
{
    __shared__ u16 Ksh[192][72];
    __shared__ u16 Vt[64][200];
    const int tid = threadIdx.x;
    const int h = blockIdx.y, kvh = h >> 1;
    const int t0 = blockIdx.x * 64;
    for (int i = 0; i < 6; ++i) {
        int idx = i * 256 + tid;
        int j = idx >> 3, d0 = (idx & 7) * 8;
        int kt = t0 - 127 + j;
        s16x8 val = {0,0,0,0,0,0,0,0};
        if (kt >= 0) val = *(const s16x8*)(knb + (size_t)kt * 256 + kvh * 64 + d0);
        *(s16x8*)&Ksh[j][d0] = val;
    }
    for (int cch = 0; cch < 6; ++cch) {
        int w  = cch * 32 + (tid & 31);
        int d0 = (tid >> 5) * 8;
        int kt = t0 - 127 + w;
        s16x8 val = {0,0,0,0,0,0,0,0};
        if (kt >= 0) val = *(const s16x8*)(vb + (size_t)kt * 256 + kvh * 64 + d0);
#pragma unroll
        for (int jj = 0; jj < 8; ++jj) Vt[d0 + jj][w] = ((const u16*)&val)[jj];
    }
    __syncthreads();
    const int wv = tid >> 6, lane = tid & 63;
    const int q = lane & 15, g = lane >> 4;
    const int tw = t0 + wv * 16;
    const int t = tw + q;
    const u16* qp = qnb + (size_t)t * 512 + h * 64;
    s16x8 qf0 = *(const s16x8*)(qp + g * 8);
    s16x8 qf1 = *(const s16x8*)(qp + 32 + g * 8);
    float s[9][4];
    float mx = -INFINITY;
    for (int wt = 0; wt < 9; ++wt) {
        int ldsrow = wv * 16 + wt * 16 + q;
        s16x8 kf0 = *(const s16x8*)&Ksh[ldsrow][g * 8];
        s16x8 kf1 = *(const s16x8*)&Ksh[ldsrow][32 + g * 8];
        f32x4 accv = {0, 0, 0, 0};
        accv = __builtin_amdgcn_mfma_f32_16x16x32_bf16(kf0, qf0, accv, 0, 0, 0);
        accv = __builtin_amdgcn_mfma_f32_16x16x32_bf16(kf1, qf1, accv, 0, 0, 0);
#pragma unroll
        for (int r = 0; r < 4; ++r) {
            int woff = wt * 16 + g * 4 + r;
            int key  = tw - 127 + woff;
            bool ok = (woff >= q) && (woff <= q + 127) && (key >= 0);
            float sv = ok ? accv[r] * 0.125f : -INFINITY;
            s[wt][r] = sv;
            mx = fmaxf(mx, sv);
        }
    }
    mx = fmaxf(mx, __shfl_xor(mx, 16));
    mx = fmaxf(mx, __shfl_xor(mx, 32));
    float sum = 0.f;
    s16x4 pb[9];
    for (int wt = 0; wt < 9; ++wt) {
#pragma unroll
        for (int r = 0; r < 4; ++r) {
            float p = __expf(s[wt][r] - mx);
            sum += p;
            pb[wt][r] = (short)f2b(p);
        }
    }
    sum += __shfl_xor(sum, 16);
    sum += __shfl_xor(sum, 32);
    float inv = 1.0f / sum;
    f32x4 oacc[4];
#pragma unroll
    for (int dt = 0; dt < 4; ++dt) {
        f32x4 a = {0, 0, 0, 0};
        for (int wt = 0; wt < 9; ++wt) {
            int col = wv * 16 + wt * 16 + g * 4;
            s16x4 vf = *(const s16x4*)&Vt[dt * 16 + q][col];
            a = __builtin_amdgcn_mfma_f32_16x16x16bf16_1k(vf, pb[wt], a, 0, 0, 0);
        }
        oacc[dt] = a;
    }
    __syncthreads();
    float (*Osh)[16][68] = (float (*)[16][68])&Ksh[0][0];
#pragma unroll
    for (int dt = 0; dt < 4; ++dt)
#pragma unroll
        for (int r = 0; r < 4; ++r)
            Osh[wv][q][dt * 16 + g * 4 + r] = oacc[dt][r] * inv;
    __syncthreads();
    const int qq = lane >> 2, dd0 = (lane & 3) * 16;
    u16* op = attb + (size_t)(tw + qq) * 512 + h * 64 + dd0;
#pragma unroll
    for (int jj = 0; jj < 4; ++jj) {
        float4 vvv = *(const float4*)&Osh[wv][qq][dd0 + jj * 4];
        ushort4 ov = { f2b(vvv.x), f2b(vvv.y), f2b(vvv.z), f2b(vvv.w) };
        *(ushort4*)(op + jj * 4) = ov;
    }
}

// ---------------------------------------------------------------------------
// K3: output projection. C f32 [2048][512] = attb bf16 @ Wo (f32, transpose-
// cast on stage). Same tile scheme as K1 but A is already bf16.
// ---------------------------------------------------------------------------
__global__ __launch_bounds__(256) void oproj(const u16* __restrict__ A,
    const float* __restrict__ Wo, float* __restrict__ C)
{
    __shared__ u16 Ash[64][72];
    __shared__ u16 Bsh[64][72];
    const int tid = threadIdx.x;
    const int m0 = blockIdx.y * 64, n0 = blockIdx.x * 64;
    const int lane = tid & 63, wv = tid >> 6;
    const int q = lane & 15, g = lane >> 4;
    const int wm = (wv & 1) * 32, wn = (wv >> 1) * 32;
    const int sr = tid >> 2, sc = (tid & 3) * 16;
    f32x4 acc[2][2] = {{{0,0,0,0},{0,0,0,0}},{{0,0,0,0},{0,0,0,0}}};
    for (int k0 = 0; k0 < 512; k0 += 64) {
        s16x8 a0 = *(const s16x8*)(A + (size_t)(m0 + sr) * 512 + k0 + sc);
        s16x8 a1 = *(const s16x8*)(A + (size_t)(m0 + sr) * 512 + k0 + sc + 8);
        float4 b0 = *(const float4*)(Wo + (size_t)(k0 + sr) * 512 + n0 + sc);
        float4 b1 = *(const float4*)(Wo + (size_t)(k0 + sr) * 512 + n0 + sc + 4);
        float4 b2 = *(const float4*)(Wo + (size_t)(k0 + sr) * 512 + n0 + sc + 8);
        float4 b3 = *(const float4*)(Wo + (size_t)(k0 + sr) * 512 + n0 + sc + 12);
        __syncthreads();
        *(s16x8*)&Ash[sr][sc]     = a0;
        *(s16x8*)&Ash[sr][sc + 8] = a1;
        Bsh[sc + 0][sr]  = f2b(b0.x); Bsh[sc + 1][sr]  = f2b(b0.y);
        Bsh[sc + 2][sr]  = f2b(b0.z); Bsh[sc + 3][sr]  = f2b(b0.w);
        Bsh[sc + 4][sr]  = f2b(b1.x); Bsh[sc + 5][sr]  = f2b(b1.y);
        Bsh[sc + 6][sr]  = f2b(b1.z); Bsh[sc + 7][sr]  = f2b(b1.w);
        Bsh[sc + 8][sr]  = f2b(b2.x); Bsh[sc + 9][sr]  = f2b(b2.y);
        Bsh[sc + 10][sr] = f2b(b2.z); Bsh[sc + 11][sr] = f2b(b2.w);
        Bsh[sc + 12][sr] = f2b(b3.x); Bsh[sc + 13][sr] = f2b(b3.y);
        Bsh[sc + 14][sr] = f2b(b3.z); Bsh[sc + 15][sr] = f2b(b3.w);
        __syncthreads();
#pragma unroll
        for (int kk = 0; kk < 64; kk += 32) {
            s16x8 af0 = *(const s16x8*)&Ash[wm + q][kk + g*8];
            s16x8 af1 = *(const s16x8*)&Ash[wm + 16 + q][kk + g*8];
            s16x8 bf0 = *(const s16x8*)&Bsh[wn + q][kk + g*8];
            s16x8 bf1 = *(const s16x8*)&Bsh[wn + 16 + q][kk + g*8];
            acc[0][0] = __builtin_amdgcn_mfma_f32_16x16x32_bf16(af0, bf0, acc[0][0], 0, 0, 0);
            acc[0][1] = __builtin_amdgcn_mfma_f32_16x16x32_bf16(af0, bf1, acc[0][1], 0, 0, 0);
            acc[1][0] = __builtin_amdgcn_mfma_f32_16x16x32_bf16(af1, bf0, acc[1][0], 0, 0, 0);
            acc[1][1] = __builtin_amdgcn_mfma_f32_16x16x32_bf16(af1, bf1, acc[1][1], 0, 0, 0);
        }
    }
#pragma unroll
    for (int mt = 0; mt < 2; ++mt)
#pragma unroll
        for (int nt = 0; nt < 2; ++nt)
#pragma unroll
            for (int r = 0; r < 4; ++r)
                C[(size_t)(m0 + wm + mt*16 + g*4 + r) * 512 + n0 + wn + nt*16 + q] = acc[mt][nt][r];
}

// ---------------------------------------------------------------------------
// Workspace (6 MB bf16): qnb [2048*512] | knb [2048*256] | vb [2048*256]
//                        | attb [2048*512]
// ---------------------------------------------------------------------------
extern "C" void kernel_launch(void* const* d_in, const int* in_sizes, int n_in,
                              void* d_out, int out_size, void* d_ws, size_t ws_size,
                              hipStream_t stream)
{
    const float* x    = (const float*)d_in[0];
    const float* Wq   = (const float*)d_in[1];
    const float* Wk   = (const float*)d_in[2];
    const float* Wv   = (const float*)d_in[3];
    const float* Wo   = (const float*)d_in[4];
    const float* qw   = (const float*)d_in[5];
    const float* kw   = (const float*)d_in[6];
    const float* cosT = (const float*)d_in[7];
    const float* sinT = (const float*)d_in[8];

    u16* ws   = (u16*)d_ws;
    u16* qnb  = ws;                             // 2048*512
    u16* knb  = qnb + (size_t)2048 * 512;       // 2048*256
    u16* vb   = knb + (size_t)2048 * 256;       // 2048*256
    u16* attb = vb  + (size_t)2048 * 256;       // 2048*512

    dim3 blk(256);
    hipLaunchKernelGGL(qkv_fused, dim3(16, 32), blk, 0, stream,
                       x, Wq, Wk, Wv, cosT, sinT, qw, kw, qnb, knb, vb);
    hipLaunchKernelGGL(swa_mfma, dim3(32, 8), blk, 0, stream, qnb, knb, vb, attb);
    hipLaunchKernelGGL(oproj, dim3(8, 32), blk, 0, stream, attb, Wo, (float*)d_out);
}

// Round 5
// 44.903 us; speedup vs baseline: 1.0428x; 1.0428x over previous
//
#include <hip/hip_runtime.h>
#include <hip/hip_bf16.h>
#include <math.h>

typedef float  f32x4  __attribute__((ext_vector_type(4)));
typedef short  s16x4  __attribute__((ext_vector_type(4)));
typedef short  s16x8  __attribute__((ext_vector_type(8)));
typedef unsigned short u16;

__device__ inline u16 f2b(float f) {
    __hip_bfloat16 h = __float2bfloat16(f);
    return *reinterpret_cast<u16*>(&h);
}

// ---------------------------------------------------------------------------
// K0: prep. blocks 0-191: transpose-cast weights -> Wt [1024][512] bf16
// (rows 0-511 Wq^T | 512-767 Wk^T | 768-1023 Wv^T), Wot [512][512] = Wo^T.
// blocks 192-703: cast x -> xb bf16 (8 elems/thread).
// ---------------------------------------------------------------------------
__global__ __launch_bounds__(256) void prep(const float* __restrict__ x,
    const float* __restrict__ Wq, const float* __restrict__ Wk,
    const float* __restrict__ Wv, const float* __restrict__ Wo,
    u16* __restrict__ xb, u16* __restrict__ Wt, u16* __restrict__ Wot)
{
    const int tid = threadIdx.x, bid = blockIdx.x;
    if (bid >= 192) {   // x cast
        int i = ((bid - 192) * 256 + tid) * 8;
        float4 v0 = *(const float4*)(x + i);
        float4 v1 = *(const float4*)(x + i + 4);
        ushort4 o0 = { f2b(v0.x), f2b(v0.y), f2b(v0.z), f2b(v0.w) };
        ushort4 o1 = { f2b(v1.x), f2b(v1.y), f2b(v1.z), f2b(v1.w) };
        *(ushort4*)(xb + i)     = o0;
        *(ushort4*)(xb + i + 4) = o1;
        return;
    }
    __shared__ u16 Tsh[64][72];
    const float* src; u16* dst; int N, base, kt, nt;
    if (bid < 64)       { src = Wq; dst = Wt;  N = 512; base = 0;   kt = bid >> 3;       nt = bid & 7; }
    else if (bid < 96)  { src = Wk; dst = Wt;  N = 256; base = 512; kt = (bid-64) >> 2;  nt = (bid-64) & 3; }
    else if (bid < 128) { src = Wv; dst = Wt;  N = 256; base = 768; kt = (bid-96) >> 2;  nt = (bid-96) & 3; }
    else                { src = Wo; dst = Wot; N = 512; base = 0;   kt = (bid-128) >> 3; nt = (bid-128) & 7; }
    const int k0 = kt * 64, n0 = nt * 64;
    const int r = tid >> 2, c0 = (tid & 3) * 16;
#pragma unroll
    for (int j = 0; j < 4; ++j) {
        float4 v = *(const float4*)(src + (size_t)(k0 + r) * N + n0 + c0 + j * 4);
        Tsh[c0 + j*4 + 0][r] = f2b(v.x);
        Tsh[c0 + j*4 + 1][r] = f2b(v.y);
        Tsh[c0 + j*4 + 2][r] = f2b(v.z);
        Tsh[c0 + j*4 + 3][r] = f2b(v.w);
    }
    __syncthreads();
    const int n = tid >> 2, kc = (tid & 3) * 16;
    u16* op = dst + (size_t)(base + n0 + n) * 512 + k0 + kc;
    *(s16x8*)(op)     = *(const s16x8*)&Tsh[n][kc];
    *(s16x8*)(op + 8) = *(const s16x8*)&Tsh[n][kc + 8];
}

// ---------------------------------------------------------------------------
// K1: QKV GEMM (bf16 MFMA, pre-transposed weights) + fused RoPE/RMS epilogue.
// M=2048, N=1024 (16 n-tiles = heads), K=512. 64x64 tile / 4 waves.
// n-tile bx: 0-7 q-head, 8-11 k-head, 12-15 v-head (plain cast).
// ---------------------------------------------------------------------------
__global__ __launch_bounds__(256) void qkv_gemm(const u16* __restrict__ A,
    const u16* __restrict__ Bt, const float* __restrict__ cosT,
    const float* __restrict__ sinT, const float* __restrict__ qw,
    const float* __restrict__ kw, u16* __restrict__ qnb,
    u16* __restrict__ knb, u16* __restrict__ vb)
{
    __shared__ u16 Ash[64][72];
    __shared__ u16 Bsh[64][72];
    __shared__ float Osh[64][68];
    const int tid = threadIdx.x;
    const int bx = blockIdx.x;
    const int m0 = blockIdx.y * 64, n0b = bx * 64;
    const int lane = tid & 63, wv = tid >> 6;
    const int q = lane & 15, g = lane >> 4;
    const int wm = (wv & 1) * 32, wn = (wv >> 1) * 32;
    const int sr = tid >> 2, sc = (tid & 3) * 16;
    f32x4 acc[2][2] = {{{0,0,0,0},{0,0,0,0}},{{0,0,0,0},{0,0,0,0}}};
    for (int k0 = 0; k0 < 512; k0 += 64) {
        s16x8 a0 = *(const s16x8*)(A  + (size_t)(m0 + sr)  * 512 + k0 + sc);
        s16x8 a1 = *(const s16x8*)(A  + (size_t)(m0 + sr)  * 512 + k0 + sc + 8);
        s16x8 b0 = *(const s16x8*)(Bt + (size_t)(n0b + sr) * 512 + k0 + sc);
        s16x8 b1 = *(const s16x8*)(Bt + (size_t)(n0b + sr) * 512 + k0 + sc + 8);
        __syncthreads();
        *(s16x8*)&Ash[sr][sc]     = a0;
        *(s16x8*)&Ash[sr][sc + 8] = a1;
        *(s16x8*)&Bsh[sr][sc]     = b0;
        *(s16x8*)&Bsh[sr][sc + 8] = b1;
        __syncthreads();
#pragma unroll
        for (int kk = 0; kk < 64; kk += 32) {
            s16x8 af0 = *(const s16x8*)&Ash[wm + q][kk + g*8];
            s16x8 af1 = *(const s16x8*)&Ash[wm + 16 + q][kk + g*8];
            s16x8 bf0 = *(const s16x8*)&Bsh[wn + q][kk + g*8];
            s16x8 bf1 = *(const s16x8*)&Bsh[wn + 16 + q][kk + g*8];
            acc[0][0] = __builtin_amdgcn_mfma_f32_16x16x32_bf16(af0, bf0, acc[0][0], 0, 0, 0);
            acc[0][1] = __builtin_amdgcn_mfma_f32_16x16x32_bf16(af0, bf1, acc[0][1], 0, 0, 0);
            acc[1][0] = __builtin_amdgcn_mfma_f32_16x16x32_bf16(af1, bf0, acc[1][0], 0, 0, 0);
            acc[1][1] = __builtin_amdgcn_mfma_f32_16x16x32_bf16(af1, bf1, acc[1][1], 0, 0, 0);
        }
    }
    // acc -> Osh (row = t within tile, col = d within head)
#pragma unroll
    for (int mt = 0; mt < 2; ++mt)
#pragma unroll
        for (int nt = 0; nt < 2; ++nt)
#pragma unroll
            for (int r = 0; r < 4; ++r)
                Osh[wm + mt*16 + g*4 + r][wn + nt*16 + q] = acc[mt][nt][r];
    __syncthreads();
    // Per-row epilogue: wave wv owns rows wv*16..wv*16+15; lane = d
#pragma unroll 1
    for (int ii = 0; ii < 16; ++ii) {
        const int row = wv * 16 + ii;
        const int t = m0 + row;
        if (bx >= 12) {
            vb[(size_t)t * 256 + (bx - 12) * 64 + lane] = f2b(Osh[row][lane]);
            continue;
        }
        float y = Osh[row][lane];
        float o = Osh[row][lane ^ 32];
        float c = cosT[t * 32 + (lane & 31)];
        float s = sinT[t * 32 + (lane & 31)];
        float r = (lane < 32) ? (y * c - o * s) : (y * c + o * s);
        float ss = r * r;
#pragma unroll
        for (int off = 32; off; off >>= 1) ss += __shfl_xor(ss, off);
        float scale = rsqrtf(ss * (1.0f / 64.0f) + 1e-6f);
        if (bx < 8) qnb[(size_t)t * 512 + bx * 64 + lane]       = f2b(r * scale * qw[lane]);
        else        knb[(size_t)t * 256 + (bx - 8) * 64 + lane] = f2b(r * scale * kw[lane]);
    }
}

// ---------------------------------------------------------------------------
// K2: MFMA sliding-window attention (verified). Block = (h, 64-q tile).
// S^T = K·Q^T (16x16x32), P^T rows land in 16x16x16 k-operand layout,
// O^T = V^T·P^T, LDS transpose out.
// ---------------------------------------------------------------------------
__global__ __launch_bounds__(256) void swa_mfma(const u16* __restrict__ qnb,
    const u16* __restrict__ knb, const u16* __restrict__ vb,
    u16* __restrict__ attb)
{
    __shared__ u16 Ksh[192][72];
    __shared__ u16 Vt[64][200];
    const int tid = threadIdx.x;
    const int h = blockIdx.y, kvh = h >> 1;
    const int t0 = blockIdx.x * 64;
    for (int i = 0; i < 6; ++i) {
        int idx = i * 256 + tid;
        int j = idx >> 3, d0 = (idx & 7) * 8;
        int kt = t0 - 127 + j;
        s16x8 val = {0,0,0,0,0,0,0,0};
        if (kt >= 0) val = *(const s16x8*)(knb + (size_t)kt * 256 + kvh * 64 + d0);
        *(s16x8*)&Ksh[j][d0] = val;
    }
    for (int cch = 0; cch < 6; ++cch) {
        int w  = cch * 32 + (tid & 31);
        int d0 = (tid >> 5) * 8;
        int kt = t0 - 127 + w;
        s16x8 val = {0,0,0,0,0,0,0,0};
        if (kt >= 0) val = *(const s16x8*)(vb + (size_t)kt * 256 + kvh * 64 + d0);
#pragma unroll
        for (int jj = 0; jj < 8; ++jj) Vt[d0 + jj][w] = ((const u16*)&val)[jj];
    }
    __syncthreads();
    const int wv = tid >> 6, lane = tid & 63;
    const int q = lane & 15, g = lane >> 4;
    const int tw = t0 + wv * 16;
    const int t = tw + q;
    const u16* qp = qnb + (size_t)t * 512 + h * 64;
    s16x8 qf0 = *(const s16x8*)(qp + g * 8);
    s16x8 qf1 = *(const s16x8*)(qp + 32 + g * 8);
    float s[9][4];
    float mx = -INFINITY;
    for (int wt = 0; wt < 9; ++wt) {
        int ldsrow = wv * 16 + wt * 16 + q;
        s16x8 kf0 = *(const s16x8*)&Ksh[ldsrow][g * 8];
        s16x8 kf1 = *(const s16x8*)&Ksh[ldsrow][32 + g * 8];
        f32x4 accv = {0, 0, 0, 0};
        accv = __builtin_amdgcn_mfma_f32_16x16x32_bf16(kf0, qf0, accv, 0, 0, 0);
        accv = __builtin_amdgcn_mfma_f32_16x16x32_bf16(kf1, qf1, accv, 0, 0, 0);
#pragma unroll
        for (int r = 0; r < 4; ++r) {
            int woff = wt * 16 + g * 4 + r;
            int key  = tw - 127 + woff;
            bool ok = (woff >= q) && (woff <= q + 127) && (key >= 0);
            float sv = ok ? accv[r] * 0.125f : -INFINITY;
            s[wt][r] = sv;
            mx = fmaxf(mx, sv);
        }
    }
    mx = fmaxf(mx, __shfl_xor(mx, 16));
    mx = fmaxf(mx, __shfl_xor(mx, 32));
    float sum = 0.f;
    s16x4 pb[9];
    for (int wt = 0; wt < 9; ++wt) {
#pragma unroll
        for (int r = 0; r < 4; ++r) {
            float p = __expf(s[wt][r] - mx);
            sum += p;
            pb[wt][r] = (short)f2b(p);
        }
    }
    sum += __shfl_xor(sum, 16);
    sum += __shfl_xor(sum, 32);
    float inv = 1.0f / sum;
    f32x4 oacc[4];
#pragma unroll
    for (int dt = 0; dt < 4; ++dt) {
        f32x4 a = {0, 0, 0, 0};
        for (int wt = 0; wt < 9; ++wt) {
            int col = wv * 16 + wt * 16 + g * 4;
            s16x4 vf = *(const s16x4*)&Vt[dt * 16 + q][col];
            a = __builtin_amdgcn_mfma_f32_16x16x16bf16_1k(vf, pb[wt], a, 0, 0, 0);
        }
        oacc[dt] = a;
    }
    __syncthreads();
    float (*Osh)[16][68] = (float (*)[16][68])&Ksh[0][0];
#pragma unroll
    for (int dt = 0; dt < 4; ++dt)
#pragma unroll
        for (int r = 0; r < 4; ++r)
            Osh[wv][q][dt * 16 + g * 4 + r] = oacc[dt][r] * inv;
    __syncthreads();
    const int qq = lane >> 2, dd0 = (lane & 3) * 16;
    u16* op = attb + (size_t)(tw + qq) * 512 + h * 64 + dd0;
#pragma unroll
    for (int jj = 0; jj < 4; ++jj) {
        float4 vvv = *(const float4*)&Osh[wv][qq][dd0 + jj * 4];
        ushort4 ov = { f2b(vvv.x), f2b(vvv.y), f2b(vvv.z), f2b(vvv.w) };
        *(ushort4*)(op + jj * 4) = ov;
    }
}

// ---------------------------------------------------------------------------
// K3: output projection. C f32 = attb bf16 @ Wot^T (pre-transposed bf16).
// ---------------------------------------------------------------------------
__global__ __launch_bounds__(256) void oproj(const u16* __restrict__ A,
    const u16* __restrict__ Bt, float* __restrict__ C)
{
    __shared__ u16 Ash[64][72];
    __shared__ u16 Bsh[64][72];
    const int tid = threadIdx.x;
    const int m0 = blockIdx.y * 64, n0 = blockIdx.x * 64;
    const int lane = tid & 63, wv = tid >> 6;
    const int q = lane & 15, g = lane >> 4;
    const int wm = (wv & 1) * 32, wn = (wv >> 1) * 32;
    const int sr = tid >> 2, sc = (tid & 3) * 16;
    f32x4 acc[2][2] = {{{0,0,0,0},{0,0,0,0}},{{0,0,0,0},{0,0,0,0}}};
    for (int k0 = 0; k0 < 512; k0 += 64) {
        s16x8 a0 = *(const s16x8*)(A  + (size_t)(m0 + sr) * 512 + k0 + sc);
        s16x8 a1 = *(const s16x8*)(A  + (size_t)(m0 + sr) * 512 + k0 + sc + 8);
        s16x8 b0 = *(const s16x8*)(Bt + (size_t)(n0 + sr) * 512 + k0 + sc);
        s16x8 b1 = *(const s16x8*)(Bt + (size_t)(n0 + sr) * 512 + k0 + sc + 8);
        __syncthreads();
        *(s16x8*)&Ash[sr][sc]     = a0;
        *(s16x8*)&Ash[sr][sc + 8] = a1;
        *(s16x8*)&Bsh[sr][sc]     = b0;
        *(s16x8*)&Bsh[sr][sc + 8] = b1;
        __syncthreads();
#pragma unroll
        for (int kk = 0; kk < 64; kk += 32) {
            s16x8 af0 = *(const s16x8*)&Ash[wm + q][kk + g*8];
            s16x8 af1 = *(const s16x8*)&Ash[wm + 16 + q][kk + g*8];
            s16x8 bf0 = *(const s16x8*)&Bsh[wn + q][kk + g*8];
            s16x8 bf1 = *(const s16x8*)&Bsh[wn + 16 + q][kk + g*8];
            acc[0][0] = __builtin_amdgcn_mfma_f32_16x16x32_bf16(af0, bf0, acc[0][0], 0, 0, 0);
            acc[0][1] = __builtin_amdgcn_mfma_f32_16x16x32_bf16(af0, bf1, acc[0][1], 0, 0, 0);
            acc[1][0] = __builtin_amdgcn_mfma_f32_16x16x32_bf16(af1, bf0, acc[1][0], 0, 0, 0);
            acc[1][1] = __builtin_amdgcn_mfma_f32_16x16x32_bf16(af1, bf1, acc[1][1], 0, 0, 0);
        }
    }
#pragma unroll
    for (int mt = 0; mt < 2; ++mt)
#pragma unroll
        for (int nt = 0; nt < 2; ++nt)
#pragma unroll
            for (int r = 0; r < 4; ++r)
                C[(size_t)(m0 + wm + mt*16 + g*4 + r) * 512 + n0 + wn + nt*16 + q] = acc[mt][nt][r];
}

// ---------------------------------------------------------------------------
// Workspace: xb [1M u16] | Wt [512K u16] | Wot [256K u16] | qnb [1M] |
//            knb [512K] | vb [512K] | attb [1M]  ≈ 9.5 MB
// ---------------------------------------------------------------------------
extern "C" void kernel_launch(void* const* d_in, const int* in_sizes, int n_in,
                              void* d_out, int out_size, void* d_ws, size_t ws_size,
                              hipStream_t stream)
{
    const float* x    = (const float*)d_in[0];
    const float* Wq   = (const float*)d_in[1];
    const float* Wk   = (const float*)d_in[2];
    const float* Wv   = (const float*)d_in[3];
    const float* Wo   = (const float*)d_in[4];
    const float* qw   = (const float*)d_in[5];
    const float* kw   = (const float*)d_in[6];
    const float* cosT = (const float*)d_in[7];
    const float* sinT = (const float*)d_in[8];

    u16* ws   = (u16*)d_ws;
    u16* xb   = ws;                              // 2048*512
    u16* Wt   = xb   + (size_t)2048 * 512;       // 1024*512
    u16* Wot  = Wt   + (size_t)1024 * 512;       // 512*512
    u16* qnb  = Wot  + (size_t)512 * 512;        // 2048*512
    u16* knb  = qnb  + (size_t)2048 * 512;       // 2048*256
    u16* vb   = knb  + (size_t)2048 * 256;       // 2048*256
    u16* attb = vb   + (size_t)2048 * 256;       // 2048*512

    dim3 blk(256);
    hipLaunchKernelGGL(prep, dim3(704), blk, 0, stream, x, Wq, Wk, Wv, Wo, xb, Wt, Wot);
    hipLaunchKernelGGL(qkv_gemm, dim3(16, 32), blk, 0, stream,
                       xb, Wt, cosT, sinT, qw, kw, qnb, knb, vb);
    hipLaunchKernelGGL(swa_mfma, dim3(32, 8), blk, 0, stream, qnb, knb, vb, attb);
    hipLaunchKernelGGL(oproj, dim3(8, 32), blk, 0, stream, attb, Wot, (float*)d_out);
}